// Round 7
// baseline (2152.715 us; speedup 1.0000x reference)
//
#include <hip/hip_runtime.h>

// VQProsodyEncoder on gfx950: 13x conv1d(K=5) as implicit-GEMM f16 MFMA,
// fused maxpool(8), VQ via fused (-2*z.c + |c|^2) GEMM + argmin + gather.
// Activations: channel-last f16 [B][T+4][C] with 2-row zero halos.
// R7: BK=64 phases (6 barriers/block, was 12), B tile = two 32-ci sub-tiles
// each with R6's measured-zero-conflict XOR swizzle; A (weights) in regs from
// L2 (tiled frags); launch_bounds(256,4) -> 4 blocks/CU (R4 measured 84 VGPR).
// Epilogue modes: 0=store f16, 1=store pooled (maxpool8 fused), 2=argmin.

typedef _Float16 f16;
typedef __attribute__((ext_vector_type(8))) _Float16 half8;
typedef __attribute__((ext_vector_type(4))) _Float16 half4;
typedef __attribute__((ext_vector_type(4))) float float4v;
typedef unsigned long long u64;
typedef unsigned int u32;

__device__ __forceinline__ void async16(const void* g, void* l) {
  __builtin_amdgcn_global_load_lds(
      (const __attribute__((address_space(1))) void*)g,
      (__attribute__((address_space(3))) void*)l, 16, 0, 0);
}

__device__ __forceinline__ u32 sortable(float s) {
  u32 u = __float_as_uint(s);
  return (u & 0x80000000u) ? ~u : (u | 0x80000000u);
}

// ---------------------------------------------------------------------------
// conv as implicit GEMM: Y[b,t,o] = sum_{kt,ci} W[kt][o][ci] * X[b][t+kt-2][ci]
// block 128(M=o) x TN(N=b*t); wave w owns o-rows [32w,32w+32) x all TN.
// Wt layout: [tap][O/16][Cin/32][16][32] (one MFMA A-frag tile = 1 KB contig).
template <int NTAP, int TN, int EPI>
__global__ __launch_bounds__(256, (TN == 128 ? 4 : 6)) void conv_gemm(
    const f16* __restrict__ Xb,   // [B][T+4][Cinp], halo rows zeroed
    const f16* __restrict__ Wt,   // tiled weights
    const float* __restrict__ bias,  // [Cout] (EPI=2: |c|^2)
    const f16* __restrict__ Res,  // [B][T+4][Cout] or null (residual add)
    f16* __restrict__ Yb,         // output (EPI 0/1)
    u64* __restrict__ Pmin,       // EPI=2: partial argmin [8192][8]
    int Cinp, int Cout, int lgT, int tapshift, int relu, int OT)
{
  constexpr int RT = TN + 16;     // staged rows per sub-tile
  constexpr int NA = RT / 16;     // asyncs per sub-tile (9 or 5)
  constexpr int NJ = TN / 16;     // j-frags per wave (8 or 4)
  __shared__ __align__(16) f16 Bls[2][2][RT * 32];  // [buf][ci-par][rows*32]
  __shared__ u64 minbuf[4][TN];                     // EPI==2 only

  const int tid  = threadIdx.x;
  const int wave = tid >> 6;
  const int lane = tid & 63;
  const int T  = 1 << lgT;
  // swizzle: group = 8 t-tiles x OT o-tiles -> o-tiles sharing an X tile land
  // on the same XCD (bid%8) at the same time.
  const int G   = OT * 8;
  const int rG  = blockIdx.x % G;
  const int grp = blockIdx.x / G;
  const int o0  = (rG >> 3) << 7;
  const int n0  = (grp * 8 + (rG & 7)) * TN;
  const int b   = n0 >> lgT;
  const int t0  = n0 & (T - 1);

  const int C32 = Cinp >> 5;
  const int O16 = Cout >> 4;
  const int NP  = (C32 + 1) >> 1;   // BK=64 phases

  // staging lane mapping (R6-proven, zero measured conflicts)
  const int Rloc = lane >> 2;                       // row within 16-row async
  const int qg   = ((lane & 3) - (Rloc >> 1)) & 3;  // swizzled source chunk
  const f16* gB0 = Xb + (size_t)(b * (T + 4) + t0) * Cinp + qg * 8;

  // A fragments direct from global (L2-hot tiled weights)
  const int aoff = (lane & 15) * 32 + ((lane >> 4) << 3);
  const int o16w = (o0 >> 4) + wave * 2;

  float4v acc[2][NJ] = {};
  const int r16 = lane & 15;
  const int q   = lane >> 4;

  auto stage = [&](int c, int bufI) {
    const int lim = (c + 1 < C32) ? 2 * NA : NA;
#pragma unroll
    for (int u = wave; u < 2 * NA; u += 4) {
      if (u >= lim) break;
      const int par = (u >= NA) ? 1 : 0;
      const int r   = u - par * NA;
      async16(gB0 + (size_t)(r * 16 + Rloc) * Cinp + (c + par) * 32,
              &Bls[bufI][par][r * 512 + lane * 8]);
    }
  };

  auto compute = [&](int c32, int bufI) {
    const f16* lds = Bls[bufI][c32 & 1];
#pragma unroll
    for (int kt = 0; kt < NTAP; ++kt) {
      half8 af[2], bv[NJ];
#pragma unroll
      for (int i = 0; i < 2; ++i)
        af[i] = *(const half8*)(Wt +
            ((((size_t)kt * O16 + o16w + i) * C32 + c32) << 9) + aoff);
#pragma unroll
      for (int j = 0; j < NJ; ++j) {
        const int R = j * 16 + r16 + tapshift + kt;
        bv[j] = *(const half8*)&lds[R * 32 + (((q + (R >> 1)) & 3) << 3)];
      }
#pragma unroll
      for (int i = 0; i < 2; ++i)
#pragma unroll
        for (int j = 0; j < NJ; ++j)
          acc[i][j] = __builtin_amdgcn_mfma_f32_16x16x32_f16(af[i], bv[j], acc[i][j], 0, 0, 0);
    }
  };

  stage(0, 0);
  int bufI = 0;
#pragma unroll 1
  for (int p = 0; p < NP; ++p) {
    __syncthreads();               // staging of bufI visible; bufI^1 free
    const int cn = 2 * (p + 1);
    if (cn < C32) stage(cn, bufI ^ 1);
    compute(2 * p, bufI);
    if (2 * p + 1 < C32) compute(2 * p + 1, bufI);
    bufI ^= 1;
  }

  // ---- epilogues. D[row][col]: col = lane&15, row = (lane>>4)*4 + reg ----
  const int col = lane & 15;
  const int qr4 = (lane >> 4) << 2;

  if constexpr (EPI == 2) {
    // fused argmin over this block's 128 codes, per n-column
#pragma unroll
    for (int j = 0; j < NJ; ++j) {
      float best = 3.4e38f;
      int bi = 0;
#pragma unroll
      for (int i = 0; i < 2; ++i) {
        const int o = o0 + wave * 32 + i * 16 + qr4;
        const float4v bb = *(const float4v*)&bias[o];
        float4v v = acc[i][j] + bb;
#pragma unroll
        for (int r = 0; r < 4; ++r) {
          float s = v[r];
          if (s < best) { best = s; bi = o + r; }
        }
      }
#pragma unroll
      for (int m = 16; m < 64; m <<= 1) {
        float ob = __shfl_xor(best, m);
        int oi = __shfl_xor(bi, m);
        if (ob < best || (ob == best && oi < bi)) { best = ob; bi = oi; }
      }
      if (q == 0)
        minbuf[wave][j * 16 + col] = ((u64)sortable(best) << 32) | (u32)bi;
    }
    __syncthreads();
    if (tid < TN) {
      u64 m = minbuf[0][tid];
      for (int w = 1; w < 4; ++w) m = (minbuf[w][tid] < m) ? minbuf[w][tid] : m;
      Pmin[(size_t)(n0 + tid) * 8 + (o0 >> 7)] = m;
    }
    return;
  }

#pragma unroll
  for (int i = 0; i < 2; ++i) {
    const int o = o0 + wave * 32 + i * 16 + qr4;
    const float4v bb = *(const float4v*)&bias[o];
#pragma unroll
    for (int j = 0; j < NJ; ++j) {
      const int t = t0 + j * 16 + col;
      float4v v = acc[i][j] + bb;
      if (relu) {
        v.x = fmaxf(v.x, 0.f); v.y = fmaxf(v.y, 0.f);
        v.z = fmaxf(v.z, 0.f); v.w = fmaxf(v.w, 0.f);
      }
      if (Res) {
        half4 r = *(const half4*)&Res[(size_t)(b * (T + 4) + t + 2) * Cout + o];
        v.x += (float)r.x; v.y += (float)r.y; v.z += (float)r.z; v.w += (float)r.w;
      }
      if constexpr (EPI == 1) {
        // fused maxpool8 along t (cols): butterfly over lane bits 0..2
#pragma unroll
        for (int m = 1; m < 8; m <<= 1) {
          v.x = fmaxf(v.x, __shfl_xor(v.x, m));
          v.y = fmaxf(v.y, __shfl_xor(v.y, m));
          v.z = fmaxf(v.z, __shfl_xor(v.z, m));
          v.w = fmaxf(v.w, __shfl_xor(v.w, m));
        }
        if ((col & 7) == 0) {
          const int tp = t >> 3;
          half4 h;
          h.x = (f16)v.x; h.y = (f16)v.y; h.z = (f16)v.z; h.w = (f16)v.w;
          *(half4*)&Yb[(size_t)(b * (T / 8 + 4) + tp + 2) * Cout + o] = h;
        }
      } else {
        half4 h;
        h.x = (f16)v.x; h.y = (f16)v.y; h.z = (f16)v.z; h.w = (f16)v.w;
        *(half4*)&Yb[(size_t)(b * (T + 4) + t + 2) * Cout + o] = h;
      }
    }
  }
}

// ---------------------------------------------------------------------------
// repack weights [L][O][I][5] -> [L][5][O/16][Ip/32][16][32] f16 frag tiles
__device__ __forceinline__ void repack_one(const float* wl, f16* wpl,
                                           int kt, int O, int I, int Ip,
                                           int bx, int nbx)
{
  const int n = O * Ip;
  const int C32 = Ip >> 5;
  for (int e = bx * 256 + threadIdx.x; e < n; e += nbx * 256) {
    int o = e / Ip, ip = e - o * Ip;
    float v = (ip < I) ? wl[(o * I + ip) * 5 + kt] : 0.f;
    size_t idx = ((((size_t)(o >> 4) * C32) + (ip >> 5)) << 9)
               + (o & 15) * 32 + (ip & 31);
    wpl[idx] = (f16)v;
  }
}

__global__ void repack_w(const float* __restrict__ w, f16* __restrict__ wp,
                         int O, int I, int Ip)
{
  const int l = blockIdx.y / 5, kt = blockIdx.y % 5;
  repack_one(w + (size_t)l * O * I * 5, wp + (size_t)blockIdx.y * O * Ip,
             kt, O, I, Ip, blockIdx.x, gridDim.x);
}

__global__ void repack_w2(const float* __restrict__ w1, f16* __restrict__ wp1,
                          const float* __restrict__ w2, f16* __restrict__ wp2)
{
  const int l = blockIdx.y / 5, kt = blockIdx.y % 5;
  const float* w = (l < 6) ? w1 : w2;
  f16* wp = (l < 6) ? wp1 : wp2;
  const int ll = (l < 6) ? l : l - 6;
  repack_one(w + (size_t)ll * 384 * 384 * 5,
             wp + ((size_t)ll * 5 + kt) * 384 * 384,
             kt, 384, 384, 384, blockIdx.x, gridDim.x);
}

// codebook [1024][256] -> tiled [64][8][16][32] of -2c, plus |c|^2
__global__ void cb_repack(const float* __restrict__ cb,
                          f16* __restrict__ wcb, float* __restrict__ cnorm)
{
  int row = blockIdx.x;
  int lane = threadIdx.x;  // 64
  float4v c = *(const float4v*)&cb[(size_t)row * 256 + lane * 4];
  half4 h;
  h.x = (f16)(-2.f * c.x); h.y = (f16)(-2.f * c.y);
  h.z = (f16)(-2.f * c.z); h.w = (f16)(-2.f * c.w);
  int ip = lane * 4;
  size_t idx = (((size_t)(row >> 4) * 8 + (ip >> 5)) << 9)
             + (row & 15) * 32 + (ip & 31);
  *(half4*)&wcb[idx] = h;
  float s = c.x * c.x + c.y * c.y + c.z * c.z + c.w * c.w;
  for (int off = 32; off > 0; off >>= 1) s += __shfl_down(s, off);
  if (lane == 0) cnorm[row] = s;
}

__global__ void mel_to_f16(const float* __restrict__ mel,  // [32][2048][80]
                           f16* __restrict__ out)           // [32][2052][96]
{
  int idx = blockIdx.x * 256 + threadIdx.x;
  if (idx >= 32 * 2052 * 12) return;
  int c8 = idx % 12;
  int r  = idx / 12;
  int tt = r % 2052;
  int b  = r / 2052;
  int t  = tt - 2;
  bool trow = (t >= 0) && (t < 2048);
  half8 hv;
#pragma unroll
  for (int e = 0; e < 8; ++e) {
    int m = c8 * 8 + e;
    float v = (trow && m < 80) ? mel[((size_t)b * 2048 + t) * 80 + m] : 0.f;
    hv[e] = (f16)v;
  }
  *(half8*)&out[((size_t)b * 2052 + tt) * 96 + c8 * 8] = hv;
}

__global__ void halo_zero(f16* a0, f16* a1, f16* b0, f16* b1, f16* zb,
                          float* accum)
{
  int bid = blockIdx.x;  // 5 bufs * 32 batches * 4 rows = 640
  if (bid == 0 && threadIdx.x == 0) { accum[0] = 0.f; accum[1] = 0.f; }
  int buf = bid >> 7;
  int r = bid & 127;
  int bb = r >> 2;
  int k = r & 3;
  f16* p; int T4, C;
  if      (buf == 0) { p = a0; T4 = 2052; C = 384; }
  else if (buf == 1) { p = a1; T4 = 2052; C = 384; }
  else if (buf == 2) { p = b0; T4 = 260;  C = 384; }
  else if (buf == 3) { p = b1; T4 = 260;  C = 384; }
  else               { p = zb; T4 = 260;  C = 256; }
  int tt = (k < 2) ? k : (T4 - 4 + k);
  f16* rowp = p + ((size_t)bb * T4 + tt) * C;
  for (int c = threadIdx.x; c < C; c += 256) rowp[c] = (f16)0.f;
}

__global__ void argmin8(const u64* __restrict__ P, int* __restrict__ idxb)
{
  int r = blockIdx.x * 256 + threadIdx.x;
  if (r >= 8192) return;
  const u64* p = P + (size_t)r * 8;
  u64 m = p[0];
#pragma unroll
  for (int k = 1; k < 8; ++k) m = (p[k] < m) ? p[k] : m;
  idxb[r] = (int)(m & 0xffffffffu);
}

__global__ void vq_gather(const f16* __restrict__ zeb,   // [32][260][256]
                          const float* __restrict__ cb,  // [1024][256]
                          const int* __restrict__ idx,
                          float* __restrict__ zq,         // [8192][256]
                          float* __restrict__ accum)
{
  int row = blockIdx.x;
  int lane = threadIdx.x;  // 64
  int b = row >> 8, t = row & 255;
  int j = idx[row];
  half4 zh = *(const half4*)&zeb[((size_t)(b * 260 + t + 2)) * 256 + lane * 4];
  float4v qv = *(const float4v*)&cb[(size_t)j * 256 + lane * 4];
  *(float4v*)&zq[(size_t)row * 256 + lane * 4] = qv;  // zq = q exactly (STE)
  float dx = (float)zh.x - qv.x, dy = (float)zh.y - qv.y;
  float dz = (float)zh.z - qv.z, dw = (float)zh.w - qv.w;
  float s = dx * dx + dy * dy + dz * dz + dw * dw;
  for (int off = 32; off > 0; off >>= 1) s += __shfl_down(s, off);
  if (lane == 0) atomicAdd(accum, s);
}

__global__ void finalize_loss(const float* __restrict__ accum,
                              float* __restrict__ out2)
{
  float c = accum[0] * (1.0f / 2097152.0f);  // mean over 32*256*256
  out2[0] = c;   // commit_loss
  out2[1] = c;   // vq_loss (== commit_loss numerically)
}

// ---------------------------------------------------------------------------
extern "C" void kernel_launch(void* const* d_in, const int* in_sizes, int n_in,
                              void* d_out, int out_size, void* d_ws, size_t ws_size,
                              hipStream_t stream)
{
  (void)in_sizes; (void)n_in; (void)out_size;
  const float* mel    = (const float*)d_in[0];
  const float* w_pre  = (const float*)d_in[1];
  const float* b_pre  = (const float*)d_in[2];
  const float* w_b1   = (const float*)d_in[3];
  const float* b_b1   = (const float*)d_in[4];
  const float* w_b2   = (const float*)d_in[5];
  const float* b_b2   = (const float*)d_in[6];
  const float* w_post = (const float*)d_in[7];
  const float* b_post = (const float*)d_in[8];
  const float* cbk    = (const float*)d_in[9];
  float* out = (float*)d_out;

  size_t off = 0;
  auto carve = [&](size_t bytes) -> char* {
    char* p = (char*)d_ws + off;
    off += (bytes + 255) & ~(size_t)255;
    return p;
  };
  f16*   wpPre  = (f16*)carve((size_t)5 * 384 * 96 * 2);
  f16*   wpB1   = (f16*)carve((size_t)6 * 5 * 384 * 384 * 2);
  f16*   wpB2   = (f16*)carve((size_t)6 * 5 * 384 * 384 * 2);
  f16*   wpPost = (f16*)carve((size_t)5 * 256 * 384 * 2);
  f16*   wpCb   = (f16*)carve((size_t)1024 * 256 * 2);
  float* cnorm  = (float*)carve(1024 * 4);
  float* accum  = (float*)carve(256);
  f16*   xmel   = (f16*)carve((size_t)32 * 2052 * 96 * 2);
  f16*   xa0    = (f16*)carve((size_t)32 * 2052 * 384 * 2);
  f16*   xa1    = (f16*)carve((size_t)32 * 2052 * 384 * 2);
  f16*   xb0    = (f16*)carve((size_t)32 * 260 * 384 * 2);
  f16*   xb1    = (f16*)carve((size_t)32 * 260 * 384 * 2);
  f16*   zeb    = (f16*)carve((size_t)32 * 260 * 256 * 2);
  u64*   pmin   = (u64*)carve((size_t)8192 * 8 * 8);
  int*   idxb   = (int*)carve((size_t)8192 * 4);
  carve(131072);  // guard: B staging over-reads past the last consumed buffer
  if (off > ws_size) return;  // ~140 MB needed

  halo_zero<<<640, 256, 0, stream>>>(xa0, xa1, xb0, xb1, zeb, accum);
  repack_w<<<dim3(144, 5),  256, 0, stream>>>(w_pre,  wpPre,  384, 80,  96);
  repack_w2<<<dim3(576, 60), 256, 0, stream>>>(w_b1, wpB1, w_b2, wpB2);
  repack_w<<<dim3(384, 5),  256, 0, stream>>>(w_post, wpPost, 256, 384, 384);
  cb_repack<<<1024, 64, 0, stream>>>(cbk, wpCb, cnorm);
  mel_to_f16<<<3078, 256, 0, stream>>>(mel, xmel);

  // phase A (T=2048, Cout=384, OT=3): 512 t-tiles * 3 = 1536 blocks
  auto convA = [&](const f16* X, const f16* W, const float* bia, const f16* R,
                   f16* YB, int Cinp, int relu) {
    conv_gemm<5, 128, 0><<<1536, 256, 0, stream>>>(X, W, bia, R, YB, nullptr,
                                                   Cinp, 384, 11, 0, relu, 3);
  };
  // phase B (T=256, Cout=384, OT=3): 128 t-tiles * 3 = 384 blocks
  auto convB = [&](const f16* X, const f16* W, const float* bia, const f16* R,
                   f16* YB, int relu) {
    conv_gemm<5, 64, 0><<<384, 256, 0, stream>>>(X, W, bia, R, YB, nullptr,
                                                 384, 384, 8, 0, relu, 3);
  };

  // pre-conv: relu(conv(mel))
  convA(xmel, wpPre, b_pre, nullptr, xa0, 96, 1);
  // stack 1 @ T=2048 (first 5; 6th fused with maxpool8)
  for (int i = 0; i < 5; ++i) {
    f16* in = (i & 1) ? xa1 : xa0;
    f16* o_ = (i & 1) ? xa0 : xa1;
    convA(in, wpB1 + (size_t)i * 5 * 384 * 384, b_b1 + i * 384, in, o_, 384, 1);
  }
  // 6th stack-1 conv + residual + maxpool8 fused -> xb0 (halo'd [32][260][384])
  conv_gemm<5, 128, 1><<<1536, 256, 0, stream>>>(
      xa1, wpB1 + (size_t)5 * 5 * 384 * 384, b_b1 + 5 * 384, xa1, xb0, nullptr,
      384, 384, 11, 0, 1, 3);
  // stack 2 @ T=256
  for (int i = 0; i < 6; ++i) {
    f16* in = (i & 1) ? xb1 : xb0;
    f16* o_ = (i & 1) ? xb0 : xb1;
    convB(in, wpB2 + (size_t)i * 5 * 384 * 384, b_b2 + i * 384, in, o_, 1);
  }
  // post-conv (Cout=256, OT=2) -> zeb f16 halo'd
  conv_gemm<5, 64, 0><<<256, 256, 0, stream>>>(xb0, wpPost, b_post, nullptr,
                                               zeb, nullptr, 384, 256, 8, 0, 0, 2);
  // VQ scores + fused argmin: dist = |c|^2 - 2 z.c (1-tap, tapshift=2), OT=8
  conv_gemm<1, 128, 2><<<512, 256, 0, stream>>>(zeb, wpCb, cnorm, nullptr,
                                                nullptr, pmin, 256, 1024, 8, 2,
                                                0, 8);
  argmin8<<<32, 256, 0, stream>>>(pmin, idxb);
  vq_gather<<<8192, 64, 0, stream>>>(zeb, cbk, idxb, out, accum);
  finalize_loss<<<1, 1, 0, stream>>>(accum, out + 2097152);
}